// Round 7
// baseline (216.029 us; speedup 1.0000x reference)
//
#include <hip/hip_runtime.h>
#include <hip/hip_fp16.h>

// TriMipEncoding: N pts, 3 planes (512^2, 16 ch), 8 mip levels, trilinear sample.
//
// Fast path (ws_size >= 33.6 MB): fp16 pyramid levels 1..6 in d_ws (layout
//   keeps the full-pyramid offsets; L0 region unused, L7 never materialized).
//   Texel = 16 halfs = 32 B. off(l) = (2^20 - (2^20 >> 2l)) / 3.
// Evidence ledger:
// R3: sampler invariant to FETCH 0 vs 122MB -> not HBM-bound.
// R4: LDS-staging taps -> real win. R5: occupancy/coalescing break -> 2.3x.
// R6/R7/R8 NEUTRAL: broadcast loads, level-sorted waves, 8-load clause.
// R9: levels 4..7 in LDS: FETCH 120->81MB, +6.5%. R10: occupancy 51->65%
//   at SAME duration -> concurrency model dead. Sampler is at its
//   divergent-gather floor (~61 us); all counters far from pipe peaks.
// R11 (this round): attack the FIXED ~23 us outside the sampler:
//   - fuse convert+tail into ONE kernel (mip_build_all): L1 from fm (fp32,
//     coalesced) cascaded L2..L6 via LDS fp32 (more accurate than before);
//   - delete L0' entirely: sampler taps level 0 from fm in fp32;
//   - L7 computed in the sampler's staging phase from staged L6.
//   3 dispatches -> 2 (~8 us/dispatch inferred from R7's +35 us for 4),
//   -25.2 MB writes, -6.3 MB L1 re-read.

typedef float        f4v   __attribute__((ext_vector_type(4)));
typedef unsigned int u32x2 __attribute__((ext_vector_type(2)));
typedef unsigned int u32x4 __attribute__((ext_vector_type(4)));

#define FM_PLANE_STRIDE (262144 * 16)   // floats per plane in fm
#define WS_PLANE_STRIDE (87376 * 16)    // floats per plane, fp32 fallback pyramid
#define PSTRIDE_H (349520 * 16)         // halfs per plane, fp16 pyramid layout
#define WS_H_BYTES (3ull * PSTRIDE_H * 2ull)
#define LVL4_OFF 348160u                // texel offset of level 4 (4..7 contiguous)

__device__ __forceinline__ unsigned lvl_off(int l) {   // texel offset of level l
    return (1048576u - (1048576u >> (2 * l))) / 3u;
}

__device__ __forceinline__ f4v ld4(const float* p) {
    return *reinterpret_cast<const f4v*>(p);
}
__device__ __forceinline__ f4v ld4nt(const float* p) {
    return __builtin_nontemporal_load(reinterpret_cast<const f4v*>(p));
}
__device__ __forceinline__ void st4(float* p, f4v v) {
    *reinterpret_cast<f4v*>(p) = v;
}
__device__ __forceinline__ void st4nt(float* p, f4v v) {
    __builtin_nontemporal_store(v, reinterpret_cast<f4v*>(p));
}
__device__ __forceinline__ f4v ldraw_h(const __half* p) {   // 8 halfs as raw f4v
    return *reinterpret_cast<const f4v*>(p);
}
__device__ __forceinline__ u32x2 pack4(f4v v) {             // 4 floats -> 4 halfs
    __half2 lo = __floats2half2_rn(v.x, v.y);
    __half2 hi = __floats2half2_rn(v.z, v.w);
    u32x2 r;
    r.x = *reinterpret_cast<unsigned*>(&lo);
    r.y = *reinterpret_cast<unsigned*>(&hi);
    return r;
}
__device__ __forceinline__ f4v h4f(const __half* p) {       // 4 halfs -> 4 floats
    u32x2 u = *reinterpret_cast<const u32x2*>(p);
    unsigned a0 = u.x, a1 = u.y;
    __half2 lo = *reinterpret_cast<__half2*>(&a0);
    __half2 hi = *reinterpret_cast<__half2*>(&a1);
    float2 flo = __half22float2(lo), fhi = __half22float2(hi);
    f4v r; r.x = flo.x; r.y = flo.y; r.z = fhi.x; r.w = fhi.y;
    return r;
}
__device__ __forceinline__ float2 up2(float rawcomp) {      // 2 packed halfs -> 2 floats
    unsigned u = __float_as_uint(rawcomp);
    __half2 hh = *reinterpret_cast<__half2*>(&u);
    return __half22float2(hh);
}

// ---------------- fp16 path ----------------

// Fused pyramid build: L1..L6 in ONE kernel. Grid (64, 3): 8x8 tiles of
// 64x64 fm texels per plane; block 1024. L1 computed from fm (fp32,
// coalesced exactly like the old convert kernel), L2..L6 cascaded through
// LDS in fp32 (each global level rounded once from the fp32 chain).
// L0' is not built (sampler taps level 0 from fm); L7 not built (sampler
// computes it from staged L6).
__global__ __launch_bounds__(1024) void mip_build_all(
    const float* __restrict__ fm, __half* __restrict__ wsh)
{
    __shared__ f4v A[32 * 32 * 4];   // [texel][q] ping buffer, 64 KB
    __shared__ f4v B[16 * 16 * 4];   // pong buffer, 16 KB

    const int tile = blockIdx.x;     // 0..63
    const int p    = blockIdx.y;
    const int ty = tile >> 3, tx = tile & 7;
    const int tid = threadIdx.x;
    const int q = tid & 3;

    __half* plane = wsh + (size_t)p * PSTRIDE_H;
    __half* L1 = plane + (size_t)lvl_off(1) * 16;
    __half* L2 = plane + (size_t)lvl_off(2) * 16;
    __half* L3 = plane + (size_t)lvl_off(3) * 16;
    __half* L4 = plane + (size_t)lvl_off(4) * 16;
    __half* L5 = plane + (size_t)lvl_off(5) * 16;
    __half* L6 = plane + (size_t)lvl_off(6) * 16;
    const float* fp = fm + (size_t)p * FM_PLANE_STRIDE;

    // Phase A: L1 tile 32x32 (4096 (texel,q) tasks, 4 iterations).
    #pragma unroll
    for (int k = 0; k < 4; ++k) {
        int s = (tid + k * 1024) >> 2;          // q invariant across k
        int ly = s >> 5, lx = s & 31;
        int gy = ty * 32 + ly, gx = tx * 32 + lx;
        const float* sp = fp + ((size_t)(2 * gy) * 512 + 2 * gx) * 16 + q * 4;
        f4v r = (ld4nt(sp) + ld4nt(sp + 16) +
                 ld4nt(sp + 512 * 16) + ld4nt(sp + 512 * 16 + 16)) * 0.25f;
        A[s * 4 + q] = r;
        *reinterpret_cast<u32x2*>(L1 + ((size_t)gy * 256 + gx) * 16 + q * 4) = pack4(r);
    }
    __syncthreads();

    {   // Phase B: L2 16x16 (1024 tasks)
        int s = tid >> 2;
        int ly = s >> 4, lx = s & 15;
        f4v r = (A[((2 * ly) * 32 + 2 * lx) * 4 + q]     + A[((2 * ly) * 32 + 2 * lx + 1) * 4 + q] +
                 A[((2 * ly + 1) * 32 + 2 * lx) * 4 + q] + A[((2 * ly + 1) * 32 + 2 * lx + 1) * 4 + q]) * 0.25f;
        B[s * 4 + q] = r;
        *reinterpret_cast<u32x2*>(L2 + ((size_t)(ty * 16 + ly) * 128 + tx * 16 + lx) * 16 + q * 4) = pack4(r);
    }
    __syncthreads();

    if (tid < 256) {   // Phase C: L3 8x8
        int s = tid >> 2;
        int ly = s >> 3, lx = s & 7;
        f4v r = (B[((2 * ly) * 16 + 2 * lx) * 4 + q]     + B[((2 * ly) * 16 + 2 * lx + 1) * 4 + q] +
                 B[((2 * ly + 1) * 16 + 2 * lx) * 4 + q] + B[((2 * ly + 1) * 16 + 2 * lx + 1) * 4 + q]) * 0.25f;
        A[s * 4 + q] = r;
        *reinterpret_cast<u32x2*>(L3 + ((size_t)(ty * 8 + ly) * 64 + tx * 8 + lx) * 16 + q * 4) = pack4(r);
    }
    __syncthreads();

    if (tid < 64) {    // Phase D: L4 4x4
        int s = tid >> 2;
        int ly = s >> 2, lx = s & 3;
        f4v r = (A[((2 * ly) * 8 + 2 * lx) * 4 + q]     + A[((2 * ly) * 8 + 2 * lx + 1) * 4 + q] +
                 A[((2 * ly + 1) * 8 + 2 * lx) * 4 + q] + A[((2 * ly + 1) * 8 + 2 * lx + 1) * 4 + q]) * 0.25f;
        B[s * 4 + q] = r;
        *reinterpret_cast<u32x2*>(L4 + ((size_t)(ty * 4 + ly) * 32 + tx * 4 + lx) * 16 + q * 4) = pack4(r);
    }
    __syncthreads();

    if (tid < 16) {    // Phase E: L5 2x2
        int s = tid >> 2;
        int ly = s >> 1, lx = s & 1;
        f4v r = (B[((2 * ly) * 4 + 2 * lx) * 4 + q]     + B[((2 * ly) * 4 + 2 * lx + 1) * 4 + q] +
                 B[((2 * ly + 1) * 4 + 2 * lx) * 4 + q] + B[((2 * ly + 1) * 4 + 2 * lx + 1) * 4 + q]) * 0.25f;
        A[s * 4 + q] = r;
        *reinterpret_cast<u32x2*>(L5 + ((size_t)(ty * 2 + ly) * 16 + tx * 2 + lx) * 16 + q * 4) = pack4(r);
    }
    __syncthreads();

    if (tid < 4) {     // Phase F: L6 1 texel per tile (global 8x8)
        f4v r = (A[0 * 4 + q] + A[1 * 4 + q] + A[2 * 4 + q] + A[3 * 4 + q]) * 0.25f;
        *reinterpret_cast<u32x2*>(L6 + ((size_t)(ty * 8 + tx)) * 16 + q * 4) = pack4(r);
    }
}

// 8-channel bilinear tap from the fp16 pyramid; levels >= 4 from LDS.
__device__ __forceinline__ void bilerp8_h(
    const __half* __restrict__ wplane, const __half* __restrict__ lds_h,
    int l, float u, float v, int h, float* o)
{
    const int sz = 512 >> l;
    const float fsz = (float)sz;
    float px = u * fsz - 0.5f;
    float py = v * fsz - 0.5f;
    float xf = floorf(px), yf = floorf(py);
    float fx = px - xf, fy = py - yf;
    int xi = (int)xf, yi = (int)yf;
    int xa = min(max(xi, 0), sz - 1);
    int xb = min(xi + 1, sz - 1);      // xi >= -1 always
    int ya = min(max(yi, 0), sz - 1);
    int yb = min(yi + 1, sz - 1);
    f4v q00, q01, q10, q11;
    if (l >= 4) {
        const __half* base = lds_h + (size_t)(lvl_off(l) - LVL4_OFF) * 16 + h * 8;
        const __half* r0 = base + (ya * sz) * 16;
        const __half* r1 = base + (yb * sz) * 16;
        q00 = ldraw_h(r0 + xa * 16);
        q01 = ldraw_h(r0 + xb * 16);
        q10 = ldraw_h(r1 + xa * 16);
        q11 = ldraw_h(r1 + xb * 16);
    } else {
        const __half* base = wplane + (size_t)lvl_off(l) * 16 + h * 8;
        const __half* r0 = base + (size_t)(ya * sz) * 16;
        const __half* r1 = base + (size_t)(yb * sz) * 16;
        q00 = ldraw_h(r0 + (size_t)xa * 16);
        q01 = ldraw_h(r0 + (size_t)xb * 16);
        q10 = ldraw_h(r1 + (size_t)xa * 16);
        q11 = ldraw_h(r1 + (size_t)xb * 16);
    }
    float gx = 1.f - fx, gy = 1.f - fy;
    float w00 = gx * gy, w01 = fx * gy, w10 = gx * fy, w11 = fx * fy;
    #pragma unroll
    for (int i = 0; i < 4; ++i) {
        float2 a = up2(q00[i]), b = up2(q01[i]), c = up2(q10[i]), d = up2(q11[i]);
        o[2 * i]     = a.x * w00 + b.x * w01 + c.x * w10 + d.x * w11;
        o[2 * i + 1] = a.y * w00 + b.y * w01 + c.y * w10 + d.y * w11;
    }
}

// Level-0 tap straight from fm (fp32, exact). Only used when l0 == 0.
__device__ __forceinline__ void bilerp8_f0(
    const float* __restrict__ fmp, float u, float v, int h, float* o)
{
    float px = u * 512.f - 0.5f;
    float py = v * 512.f - 0.5f;
    float xf = floorf(px), yf = floorf(py);
    float fx = px - xf, fy = py - yf;
    int xi = (int)xf, yi = (int)yf;
    int xa = min(max(xi, 0), 511);
    int xb = min(xi + 1, 511);
    int ya = min(max(yi, 0), 511);
    int yb = min(yi + 1, 511);
    const float* r0 = fmp + (size_t)(ya * 512) * 16 + h * 8;
    const float* r1 = fmp + (size_t)(yb * 512) * 16 + h * 8;
    f4v p00a = ld4(r0 + (size_t)xa * 16), p00b = ld4(r0 + (size_t)xa * 16 + 4);
    f4v p01a = ld4(r0 + (size_t)xb * 16), p01b = ld4(r0 + (size_t)xb * 16 + 4);
    f4v p10a = ld4(r1 + (size_t)xa * 16), p10b = ld4(r1 + (size_t)xa * 16 + 4);
    f4v p11a = ld4(r1 + (size_t)xb * 16), p11b = ld4(r1 + (size_t)xb * 16 + 4);
    float gx = 1.f - fx, gy = 1.f - fy;
    float w00 = gx * gy, w01 = fx * gy, w10 = gx * fy, w11 = fx * fy;
    #pragma unroll
    for (int i = 0; i < 4; ++i) {
        o[i]     = p00a[i] * w00 + p01a[i] * w01 + p10a[i] * w10 + p11a[i] * w11;
        o[4 + i] = p00b[i] * w00 + p01b[i] * w01 + p10b[i] * w10 + p11b[i] * w11;
    }
}

// One plane per block (blockIdx.y = p); 2 threads per point (h = tid&1),
// 512 points per 1024-thread block. LDS: this plane's levels 4..6 staged
// from global, level 7 computed in-LDS from L6. 43.5 KB -> 2 blocks/CU.
__global__ __launch_bounds__(1024) void trimip_sample_h(
    const float* __restrict__ xyz, const float* __restrict__ level,
    const float* __restrict__ fm, const __half* __restrict__ wsh,
    float* __restrict__ out, int N)
{
    __shared__ u32x4 lds[2720];       // 1360 texels * 32 B (L4..L6 staged, L7 computed)
    const int p = blockIdx.y;
    const __half* wplane = wsh + (size_t)p * PSTRIDE_H;
    for (int uidx = threadIdx.x; uidx < 2688; uidx += 1024) {
        lds[uidx] = *reinterpret_cast<const u32x4*>(
            wplane + (size_t)LVL4_OFF * 16 + (size_t)uidx * 8);
    }
    __syncthreads();
    __half* lds_h = reinterpret_cast<__half*>(lds);

    if (threadIdx.x < 64) {           // L7 (4x4) from staged L6 (8x8 at texel 1280)
        int q = threadIdx.x & 3, i = threadIdx.x >> 2;   // i: 0..15
        int y = i >> 2, x = i & 3;
        f4v r = (h4f(lds_h + (size_t)(1280 + (2 * y) * 8 + 2 * x) * 16 + q * 4) +
                 h4f(lds_h + (size_t)(1280 + (2 * y) * 8 + 2 * x + 1) * 16 + q * 4) +
                 h4f(lds_h + (size_t)(1280 + (2 * y + 1) * 8 + 2 * x) * 16 + q * 4) +
                 h4f(lds_h + (size_t)(1280 + (2 * y + 1) * 8 + 2 * x + 1) * 16 + q * 4)) * 0.25f;
        *reinterpret_cast<u32x2*>(lds_h + (size_t)(1344 + i) * 16 + q * 4) = pack4(r);
    }
    __syncthreads();

    const int n = blockIdx.x * 512 + (threadIdx.x >> 1);
    if (n >= N) return;
    const int h = threadIdx.x & 1;

    const float c0 = xyz[n * 3 + 0];
    const float c1 = xyz[n * 3 + 1];
    const float c2 = xyz[n * 3 + 2];
    const float u = (p == 0) ? c1 : c0;
    const float v = (p == 2) ? c1 : c2;

    float lv = level[n];
    lv = fminf(fmaxf(lv, 0.f), 7.f);
    float lf = floorf(lv);
    float f = lv - lf;
    int l0 = (int)lf;
    int l1 = min(l0 + 1, 7);

    float s0[8], s1[8];
    if (l0 == 0) {
        bilerp8_f0(fm + (size_t)p * FM_PLANE_STRIDE, u, v, h, s0);
    } else {
        bilerp8_h(wplane, lds_h, l0, u, v, h, s0);
    }
    bilerp8_h(wplane, lds_h, l1, u, v, h, s1);   // l1 >= 1 always

    float g = 1.f - f;
    f4v oa, ob;
    #pragma unroll
    for (int i = 0; i < 4; ++i) {
        oa[i] = s0[i] * g + s1[i] * f;
        ob[i] = s0[4 + i] * g + s1[4 + i] * f;
    }
    float* op = out + (size_t)((n * 3 + p) * 2 + h) * 8;
    st4nt(op, oa);
    st4nt(op + 4, ob);
}

// ---------------- fp32 fallback path ----------------

__device__ __forceinline__ f4v avg4(f4v a, f4v b, f4v c, f4v d) {
    return (a + b + c + d) * 0.25f;
}

__global__ __launch_bounds__(256) void mip_build_f(
    const float* __restrict__ src, float* __restrict__ dst)
{
    int t = blockIdx.x * blockDim.x + threadIdx.x;
    const int p = blockIdx.y;
    const int q = t & 3, idx = t >> 2;
    const int y = idx >> 8, x = idx & 255;
    const float* sp = src + (size_t)p * FM_PLANE_STRIDE
                          + ((size_t)(2 * y) * 512 + 2 * x) * 16 + q * 4;
    f4v r = avg4(ld4(sp), ld4(sp + 16), ld4(sp + 512 * 16), ld4(sp + 512 * 16 + 16));
    st4(dst + (size_t)p * WS_PLANE_STRIDE + ((size_t)y * 256 + x) * 16 + q * 4, r);
}

__global__ __launch_bounds__(256) void mip_tail_f(float* __restrict__ mips)
{
    const int tile = blockIdx.x, q = blockIdx.y, p = blockIdx.z;
    const int ty = tile >> 2, tx = tile & 3;
    const int tid = threadIdx.x;
    __shared__ f4v A[32 * 32];
    __shared__ f4v B[16 * 16];
    float* plane = mips + (size_t)p * WS_PLANE_STRIDE;
    const float* L1 = plane;
    float* L2 = plane + (size_t)65536 * 16;
    float* L3 = plane + (size_t)81920 * 16;
    float* L4 = plane + (size_t)86016 * 16;
    float* L5 = plane + (size_t)87040 * 16;
    float* L6 = plane + (size_t)87296 * 16;
    float* L7 = plane + (size_t)87360 * 16;

    #pragma unroll
    for (int k = 0; k < 4; ++k) {
        int li = tid + k * 256;
        int ly = li >> 5, lx = li & 31;
        int gy = ty * 32 + ly, gx = tx * 32 + lx;
        const float* sp = L1 + ((size_t)(2 * gy) * 256 + 2 * gx) * 16 + q * 4;
        f4v r = avg4(ld4(sp), ld4(sp + 16), ld4(sp + 256 * 16), ld4(sp + 256 * 16 + 16));
        A[li] = r;
        st4(L2 + ((size_t)gy * 128 + gx) * 16 + q * 4, r);
    }
    __syncthreads();
    {
        int ly = tid >> 4, lx = tid & 15;
        f4v r = avg4(A[(2 * ly) * 32 + 2 * lx],     A[(2 * ly) * 32 + 2 * lx + 1],
                     A[(2 * ly + 1) * 32 + 2 * lx], A[(2 * ly + 1) * 32 + 2 * lx + 1]);
        B[tid] = r;
        st4(L3 + ((size_t)(ty * 16 + ly) * 64 + tx * 16 + lx) * 16 + q * 4, r);
    }
    __syncthreads();
    if (tid < 64) {
        int ly = tid >> 3, lx = tid & 7;
        f4v r = avg4(B[(2 * ly) * 16 + 2 * lx],     B[(2 * ly) * 16 + 2 * lx + 1],
                     B[(2 * ly + 1) * 16 + 2 * lx], B[(2 * ly + 1) * 16 + 2 * lx + 1]);
        A[tid] = r;
        st4(L4 + ((size_t)(ty * 8 + ly) * 32 + tx * 8 + lx) * 16 + q * 4, r);
    }
    __syncthreads();
    if (tid < 16) {
        int ly = tid >> 2, lx = tid & 3;
        f4v r = avg4(A[(2 * ly) * 8 + 2 * lx],     A[(2 * ly) * 8 + 2 * lx + 1],
                     A[(2 * ly + 1) * 8 + 2 * lx], A[(2 * ly + 1) * 8 + 2 * lx + 1]);
        B[tid] = r;
        st4(L5 + ((size_t)(ty * 4 + ly) * 16 + tx * 4 + lx) * 16 + q * 4, r);
    }
    __syncthreads();
    if (tid < 4) {
        int ly = tid >> 1, lx = tid & 1;
        f4v r = avg4(B[(2 * ly) * 4 + 2 * lx],     B[(2 * ly) * 4 + 2 * lx + 1],
                     B[(2 * ly + 1) * 4 + 2 * lx], B[(2 * ly + 1) * 4 + 2 * lx + 1]);
        A[tid] = r;
        st4(L6 + ((size_t)(ty * 2 + ly) * 8 + tx * 2 + lx) * 16 + q * 4, r);
    }
    __syncthreads();
    if (tid == 0) {
        f4v r = avg4(A[0], A[1], A[2], A[3]);
        st4(L7 + ((size_t)ty * 4 + tx) * 16 + q * 4, r);
    }
}

__device__ __forceinline__ f4v bilerp_f(
    const float* __restrict__ fm, const float* __restrict__ mips,
    int p, int l, float u, float v, int q)
{
    const int sz = 512 >> l;
    const float fsz = (float)sz;
    float px = u * fsz - 0.5f;
    float py = v * fsz - 0.5f;
    float xf = floorf(px), yf = floorf(py);
    float fx = px - xf, fy = py - yf;
    int xi = (int)xf, yi = (int)yf;
    int xa = min(max(xi, 0), sz - 1);
    int xb = min(xi + 1, sz - 1);
    int ya = min(max(yi, 0), sz - 1);
    int yb = min(yi + 1, sz - 1);
    const float* base;
    if (l == 0) {
        base = fm + (size_t)p * FM_PLANE_STRIDE;
    } else {
        unsigned off = (262144u - ((unsigned)(sz * sz) << 2)) / 3u;
        base = mips + (size_t)p * WS_PLANE_STRIDE + (size_t)off * 16;
    }
    const float* r0 = base + (size_t)(ya * sz) * 16 + q * 4;
    const float* r1 = base + (size_t)(yb * sz) * 16 + q * 4;
    f4v f00 = ld4(r0 + xa * 16);
    f4v f01 = ld4(r0 + xb * 16);
    f4v f10 = ld4(r1 + xa * 16);
    f4v f11 = ld4(r1 + xb * 16);
    float gx = 1.f - fx, gy = 1.f - fy;
    return (f00 * gx + f01 * fx) * gy + (f10 * gx + f11 * fx) * fy;
}

__global__ __launch_bounds__(256) void trimip_sample_f(
    const float* __restrict__ xyz, const float* __restrict__ level,
    const float* __restrict__ fm, const float* __restrict__ mips,
    float* __restrict__ out, int N)
{
    int t = blockIdx.x * blockDim.x + threadIdx.x;
    if (t >= N * 12) return;
    const int q = t & 3;
    const int r = t >> 2;
    const int n = r / 3;
    const int p = r - n * 3;
    const float c0 = xyz[n * 3 + 0];
    const float c1 = xyz[n * 3 + 1];
    const float c2 = xyz[n * 3 + 2];
    const float u = (p == 0) ? c1 : c0;
    const float v = (p == 2) ? c1 : c2;
    float lv = level[n];
    lv = fminf(fmaxf(lv, 0.f), 7.f);
    float lf = floorf(lv);
    float f = lv - lf;
    int l0 = (int)lf;
    int l1 = min(l0 + 1, 7);
    f4v s0 = bilerp_f(fm, mips, p, l0, u, v, q);
    f4v s1 = bilerp_f(fm, mips, p, l1, u, v, q);
    f4v o = s0 * (1.f - f) + s1 * f;
    st4nt(out + (size_t)t * 4, o);
}

extern "C" void kernel_launch(void* const* d_in, const int* in_sizes, int n_in,
                              void* d_out, int out_size, void* d_ws, size_t ws_size,
                              hipStream_t stream) {
    const float* xyz   = (const float*)d_in[0];
    const float* level = (const float*)d_in[1];
    const float* fm    = (const float*)d_in[2];
    float* out = (float*)d_out;
    const int N = in_sizes[1];

    if (ws_size >= WS_H_BYTES) {
        __half* wsh = (__half*)d_ws;
        mip_build_all<<<dim3(64, 3), 1024, 0, stream>>>(fm, wsh);
        trimip_sample_h<<<dim3((N + 511) / 512, 3), 1024, 0, stream>>>(
            xyz, level, fm, wsh, out, N);
    } else {
        float* mips = (float*)d_ws;
        mip_build_f<<<dim3(1024, 3), dim3(256), 0, stream>>>(fm, mips);
        mip_tail_f<<<dim3(16, 4, 3), dim3(256), 0, stream>>>(mips);
        const int total = N * 12;
        trimip_sample_f<<<(total + 255) / 256, 256, 0, stream>>>(xyz, level, fm, mips, out, N);
    }
}

// Round 8
// 194.137 us; speedup vs baseline: 1.1128x; 1.1128x over previous
//
#include <hip/hip_runtime.h>
#include <hip/hip_fp16.h>

// TriMipEncoding: N pts, 3 planes (512^2, 16 ch), 8 mip levels, trilinear sample.
//
// Fast path (ws_size >= 33.6 MB): fp16 pyramid levels 0..6 in d_ws
//   (full-pyramid offsets; L7 never materialized in global -- computed
//   in the sampler's LDS staging from L6).
//   Texel = 16 halfs = 32 B. off(l) = (2^20 - (2^20 >> 2l)) / 3.
// Evidence ledger:
// R3: sampler invariant to FETCH 0 vs 122MB -> not HBM-bound.
// R4: LDS-staging taps -> real win. R5: occupancy/coalescing break -> 2.3x.
// R6/R7/R8 NEUTRAL: broadcast loads, level-sorted waves, 8-load clause.
// R9: levels 4..7 in LDS: FETCH 120->81MB, +6.5%.
// R10: occupancy 51->65% at SAME 61.5us -> sampler at divergent-gather
//   floor; all counters far from pipe peaks. BEST sampler config.
// R11 REGRESSED (+43% sampler): fp32-L0-from-fm made every wave run both
//   tap paths at double width + worse cache footprint. Lesson: never
//   trade hot-loop uniformity for cold-path savings.
// R12 (this round): keep R11's single-dispatch fused build but restore
//   L0' fp16 output (build = old convert+tail in ONE kernel); sampler
//   reverted to R10 exactly (all taps fp16 pyramid, L4..L6 staged to
//   LDS, L7 computed in-LDS from staged L6). 3 dispatches -> 2 with the
//   proven-best sampler untouched.

typedef float        f4v   __attribute__((ext_vector_type(4)));
typedef unsigned int u32x2 __attribute__((ext_vector_type(2)));
typedef unsigned int u32x4 __attribute__((ext_vector_type(4)));

#define FM_PLANE_STRIDE (262144 * 16)   // floats per plane in fm
#define WS_PLANE_STRIDE (87376 * 16)    // floats per plane, fp32 fallback pyramid
#define PSTRIDE_H (349520 * 16)         // halfs per plane, fp16 pyramid layout
#define WS_H_BYTES (3ull * PSTRIDE_H * 2ull)
#define LVL4_OFF 348160u                // texel offset of level 4 (4..7 contiguous)

__device__ __forceinline__ unsigned lvl_off(int l) {   // texel offset of level l
    return (1048576u - (1048576u >> (2 * l))) / 3u;
}

__device__ __forceinline__ f4v ld4(const float* p) {
    return *reinterpret_cast<const f4v*>(p);
}
__device__ __forceinline__ f4v ld4nt(const float* p) {
    return __builtin_nontemporal_load(reinterpret_cast<const f4v*>(p));
}
__device__ __forceinline__ void st4(float* p, f4v v) {
    *reinterpret_cast<f4v*>(p) = v;
}
__device__ __forceinline__ void st4nt(float* p, f4v v) {
    __builtin_nontemporal_store(v, reinterpret_cast<f4v*>(p));
}
__device__ __forceinline__ f4v ldraw_h(const __half* p) {   // 8 halfs as raw f4v
    return *reinterpret_cast<const f4v*>(p);
}
__device__ __forceinline__ u32x2 pack4(f4v v) {             // 4 floats -> 4 halfs
    __half2 lo = __floats2half2_rn(v.x, v.y);
    __half2 hi = __floats2half2_rn(v.z, v.w);
    u32x2 r;
    r.x = *reinterpret_cast<unsigned*>(&lo);
    r.y = *reinterpret_cast<unsigned*>(&hi);
    return r;
}
__device__ __forceinline__ f4v h4f(const __half* p) {       // 4 halfs -> 4 floats
    u32x2 u = *reinterpret_cast<const u32x2*>(p);
    unsigned a0 = u.x, a1 = u.y;
    __half2 lo = *reinterpret_cast<__half2*>(&a0);
    __half2 hi = *reinterpret_cast<__half2*>(&a1);
    float2 flo = __half22float2(lo), fhi = __half22float2(hi);
    f4v r; r.x = flo.x; r.y = flo.y; r.z = fhi.x; r.w = fhi.y;
    return r;
}
__device__ __forceinline__ float2 up2(float rawcomp) {      // 2 packed halfs -> 2 floats
    unsigned u = __float_as_uint(rawcomp);
    __half2 hh = *reinterpret_cast<__half2*>(&u);
    return __half22float2(hh);
}

// ---------------- fp16 path ----------------

// Fused pyramid build: L0'..L6 in ONE kernel. Grid (64, 3): 8x8 tiles of
// 64x64 fm texels per plane; block 1024. Phase A = the old convert kernel
// (fm fp32 -> L0' fp16 + L1 fp16, fp32 avg kept in LDS); then L2..L6
// cascaded through LDS in fp32 (each global level rounded once).
// L7 not built here (sampler computes it from staged L6).
__global__ __launch_bounds__(1024) void mip_build_all(
    const float* __restrict__ fm, __half* __restrict__ wsh)
{
    __shared__ f4v A[32 * 32 * 4];   // [texel][q] ping buffer, 64 KB
    __shared__ f4v B[16 * 16 * 4];   // pong buffer, 16 KB

    const int tile = blockIdx.x;     // 0..63
    const int p    = blockIdx.y;
    const int ty = tile >> 3, tx = tile & 7;
    const int tid = threadIdx.x;
    const int q = tid & 3;

    __half* plane = wsh + (size_t)p * PSTRIDE_H;
    __half* L0 = plane;
    __half* L1 = plane + (size_t)lvl_off(1) * 16;
    __half* L2 = plane + (size_t)lvl_off(2) * 16;
    __half* L3 = plane + (size_t)lvl_off(3) * 16;
    __half* L4 = plane + (size_t)lvl_off(4) * 16;
    __half* L5 = plane + (size_t)lvl_off(5) * 16;
    __half* L6 = plane + (size_t)lvl_off(6) * 16;
    const float* fp = fm + (size_t)p * FM_PLANE_STRIDE;

    // Phase A: L0' + L1 for a 32x32 L1 tile (4096 (texel,q) tasks).
    #pragma unroll
    for (int k = 0; k < 4; ++k) {
        int s = (tid + k * 1024) >> 2;          // q invariant across k
        int ly = s >> 5, lx = s & 31;
        int gy = ty * 32 + ly, gx = tx * 32 + lx;
        const float* sp = fp + ((size_t)(2 * gy) * 512 + 2 * gx) * 16 + q * 4;
        f4v a = ld4nt(sp);
        f4v b = ld4nt(sp + 16);
        f4v c = ld4nt(sp + 512 * 16);
        f4v d = ld4nt(sp + 512 * 16 + 16);
        size_t o00 = ((size_t)(2 * gy) * 512 + 2 * gx) * 16 + q * 4;
        *reinterpret_cast<u32x2*>(L0 + o00)                 = pack4(a);
        *reinterpret_cast<u32x2*>(L0 + o00 + 16)            = pack4(b);
        *reinterpret_cast<u32x2*>(L0 + o00 + 512 * 16)      = pack4(c);
        *reinterpret_cast<u32x2*>(L0 + o00 + 512 * 16 + 16) = pack4(d);
        f4v r = (a + b + c + d) * 0.25f;        // fp32 chain, single rounding
        A[s * 4 + q] = r;
        *reinterpret_cast<u32x2*>(L1 + ((size_t)gy * 256 + gx) * 16 + q * 4) = pack4(r);
    }
    __syncthreads();

    {   // Phase B: L2 16x16 (1024 tasks)
        int s = tid >> 2;
        int ly = s >> 4, lx = s & 15;
        f4v r = (A[((2 * ly) * 32 + 2 * lx) * 4 + q]     + A[((2 * ly) * 32 + 2 * lx + 1) * 4 + q] +
                 A[((2 * ly + 1) * 32 + 2 * lx) * 4 + q] + A[((2 * ly + 1) * 32 + 2 * lx + 1) * 4 + q]) * 0.25f;
        B[s * 4 + q] = r;
        *reinterpret_cast<u32x2*>(L2 + ((size_t)(ty * 16 + ly) * 128 + tx * 16 + lx) * 16 + q * 4) = pack4(r);
    }
    __syncthreads();

    if (tid < 256) {   // Phase C: L3 8x8
        int s = tid >> 2;
        int ly = s >> 3, lx = s & 7;
        f4v r = (B[((2 * ly) * 16 + 2 * lx) * 4 + q]     + B[((2 * ly) * 16 + 2 * lx + 1) * 4 + q] +
                 B[((2 * ly + 1) * 16 + 2 * lx) * 4 + q] + B[((2 * ly + 1) * 16 + 2 * lx + 1) * 4 + q]) * 0.25f;
        A[s * 4 + q] = r;
        *reinterpret_cast<u32x2*>(L3 + ((size_t)(ty * 8 + ly) * 64 + tx * 8 + lx) * 16 + q * 4) = pack4(r);
    }
    __syncthreads();

    if (tid < 64) {    // Phase D: L4 4x4
        int s = tid >> 2;
        int ly = s >> 2, lx = s & 3;
        f4v r = (A[((2 * ly) * 8 + 2 * lx) * 4 + q]     + A[((2 * ly) * 8 + 2 * lx + 1) * 4 + q] +
                 A[((2 * ly + 1) * 8 + 2 * lx) * 4 + q] + A[((2 * ly + 1) * 8 + 2 * lx + 1) * 4 + q]) * 0.25f;
        B[s * 4 + q] = r;
        *reinterpret_cast<u32x2*>(L4 + ((size_t)(ty * 4 + ly) * 32 + tx * 4 + lx) * 16 + q * 4) = pack4(r);
    }
    __syncthreads();

    if (tid < 16) {    // Phase E: L5 2x2
        int s = tid >> 2;
        int ly = s >> 1, lx = s & 1;
        f4v r = (B[((2 * ly) * 4 + 2 * lx) * 4 + q]     + B[((2 * ly) * 4 + 2 * lx + 1) * 4 + q] +
                 B[((2 * ly + 1) * 4 + 2 * lx) * 4 + q] + B[((2 * ly + 1) * 4 + 2 * lx + 1) * 4 + q]) * 0.25f;
        A[s * 4 + q] = r;
        *reinterpret_cast<u32x2*>(L5 + ((size_t)(ty * 2 + ly) * 16 + tx * 2 + lx) * 16 + q * 4) = pack4(r);
    }
    __syncthreads();

    if (tid < 4) {     // Phase F: L6 1 texel per tile (global 8x8)
        f4v r = (A[0 * 4 + q] + A[1 * 4 + q] + A[2 * 4 + q] + A[3 * 4 + q]) * 0.25f;
        *reinterpret_cast<u32x2*>(L6 + ((size_t)(ty * 8 + tx)) * 16 + q * 4) = pack4(r);
    }
}

// Issue the 4 bilinear tap loads for one level WITHOUT consuming them.
// wplane = fp16 pyramid base of this block's plane. Levels >= 4 read the
// LDS copy (levels 4..6 staged from global, 7 computed in-LDS; linear
// layout from texel LVL4_OFF).
__device__ __forceinline__ void tap_issue(
    const __half* __restrict__ wplane, const __half* __restrict__ lds_h,
    int l, float u, float v, int h,
    f4v& q00, f4v& q01, f4v& q10, f4v& q11, float& fx, float& fy)
{
    const int sz = 512 >> l;
    const float fsz = (float)sz;
    float px = u * fsz - 0.5f;
    float py = v * fsz - 0.5f;
    float xf = floorf(px), yf = floorf(py);
    fx = px - xf;
    fy = py - yf;
    int xi = (int)xf, yi = (int)yf;
    int xa = min(max(xi, 0), sz - 1);
    int xb = min(xi + 1, sz - 1);      // xi >= -1 always
    int ya = min(max(yi, 0), sz - 1);
    int yb = min(yi + 1, sz - 1);
    if (l >= 4) {
        const __half* base = lds_h + (size_t)(lvl_off(l) - LVL4_OFF) * 16 + h * 8;
        const __half* r0 = base + (ya * sz) * 16;
        const __half* r1 = base + (yb * sz) * 16;
        q00 = ldraw_h(r0 + xa * 16);
        q01 = ldraw_h(r0 + xb * 16);
        q10 = ldraw_h(r1 + xa * 16);
        q11 = ldraw_h(r1 + xb * 16);
    } else {
        const __half* base = wplane + (size_t)lvl_off(l) * 16 + h * 8;
        const __half* r0 = base + (size_t)(ya * sz) * 16;
        const __half* r1 = base + (size_t)(yb * sz) * 16;
        q00 = ldraw_h(r0 + (size_t)xa * 16);
        q01 = ldraw_h(r0 + (size_t)xb * 16);
        q10 = ldraw_h(r1 + (size_t)xa * 16);
        q11 = ldraw_h(r1 + (size_t)xb * 16);
    }
}

// One plane per block (blockIdx.y = p); 2 threads per point (h = tid&1),
// 512 points per 1024-thread block. LDS: levels 4..6 staged from global
// (2688 16B units), level 7 computed in-LDS from L6 (texels 1344..1359).
// 43.5 KB -> 2 blocks/CU x 16 waves = 32 waves/CU. Identical hot loop to
// R10 (best measured: 61.5 us).
__global__ __launch_bounds__(1024) void trimip_sample_h(
    const float* __restrict__ xyz, const float* __restrict__ level,
    const __half* __restrict__ wsh, float* __restrict__ out, int N)
{
    __shared__ u32x4 lds[2720];       // 1360 texels * 32 B
    const int p = blockIdx.y;
    const __half* wplane = wsh + (size_t)p * PSTRIDE_H;
    for (int uidx = threadIdx.x; uidx < 2688; uidx += 1024) {
        lds[uidx] = *reinterpret_cast<const u32x4*>(
            wplane + (size_t)LVL4_OFF * 16 + (size_t)uidx * 8);
    }
    __syncthreads();
    __half* lds_h = reinterpret_cast<__half*>(lds);

    if (threadIdx.x < 64) {           // L7 (4x4) from staged L6 (8x8 at texel 1280)
        int q = threadIdx.x & 3, i = threadIdx.x >> 2;   // i: 0..15
        int y = i >> 2, x = i & 3;
        f4v r = (h4f(lds_h + (size_t)(1280 + (2 * y) * 8 + 2 * x) * 16 + q * 4) +
                 h4f(lds_h + (size_t)(1280 + (2 * y) * 8 + 2 * x + 1) * 16 + q * 4) +
                 h4f(lds_h + (size_t)(1280 + (2 * y + 1) * 8 + 2 * x) * 16 + q * 4) +
                 h4f(lds_h + (size_t)(1280 + (2 * y + 1) * 8 + 2 * x + 1) * 16 + q * 4)) * 0.25f;
        *reinterpret_cast<u32x2*>(lds_h + (size_t)(1344 + i) * 16 + q * 4) = pack4(r);
    }
    __syncthreads();

    const int n = blockIdx.x * 512 + (threadIdx.x >> 1);
    if (n >= N) return;
    const int h = threadIdx.x & 1;

    const float c0 = xyz[n * 3 + 0];
    const float c1 = xyz[n * 3 + 1];
    const float c2 = xyz[n * 3 + 2];
    const float u = (p == 0) ? c1 : c0;
    const float v = (p == 2) ? c1 : c2;

    float lv = level[n];
    lv = fminf(fmaxf(lv, 0.f), 7.f);
    float lf = floorf(lv);
    float f = lv - lf;
    int l0 = (int)lf;
    int l1 = min(l0 + 1, 7);

    // Issue all 8 tap loads before consuming any.
    f4v a00, a01, a10, a11, b00, b01, b10, b11;
    float fx0, fy0, fx1, fy1;
    tap_issue(wplane, lds_h, l0, u, v, h, a00, a01, a10, a11, fx0, fy0);
    tap_issue(wplane, lds_h, l1, u, v, h, b00, b01, b10, b11, fx1, fy1);

    float s0[8], s1[8];
    {
        float gx = 1.f - fx0, gy = 1.f - fy0;
        float w00 = gx * gy, w01 = fx0 * gy, w10 = gx * fy0, w11 = fx0 * fy0;
        #pragma unroll
        for (int i = 0; i < 4; ++i) {
            float2 a = up2(a00[i]), b = up2(a01[i]), c = up2(a10[i]), d = up2(a11[i]);
            s0[2 * i]     = a.x * w00 + b.x * w01 + c.x * w10 + d.x * w11;
            s0[2 * i + 1] = a.y * w00 + b.y * w01 + c.y * w10 + d.y * w11;
        }
    }
    {
        float gx = 1.f - fx1, gy = 1.f - fy1;
        float w00 = gx * gy, w01 = fx1 * gy, w10 = gx * fy1, w11 = fx1 * fy1;
        #pragma unroll
        for (int i = 0; i < 4; ++i) {
            float2 a = up2(b00[i]), b = up2(b01[i]), c = up2(b10[i]), d = up2(b11[i]);
            s1[2 * i]     = a.x * w00 + b.x * w01 + c.x * w10 + d.x * w11;
            s1[2 * i + 1] = a.y * w00 + b.y * w01 + c.y * w10 + d.y * w11;
        }
    }

    float g = 1.f - f;
    f4v oa, ob;
    #pragma unroll
    for (int i = 0; i < 4; ++i) {
        oa[i] = s0[i] * g + s1[i] * f;
        ob[i] = s0[4 + i] * g + s1[4 + i] * f;
    }
    float* op = out + (size_t)((n * 3 + p) * 2 + h) * 8;
    st4nt(op, oa);
    st4nt(op + 4, ob);
}

// ---------------- fp32 fallback path ----------------

__device__ __forceinline__ f4v avg4(f4v a, f4v b, f4v c, f4v d) {
    return (a + b + c + d) * 0.25f;
}

__global__ __launch_bounds__(256) void mip_build_f(
    const float* __restrict__ src, float* __restrict__ dst)
{
    int t = blockIdx.x * blockDim.x + threadIdx.x;
    const int p = blockIdx.y;
    const int q = t & 3, idx = t >> 2;
    const int y = idx >> 8, x = idx & 255;
    const float* sp = src + (size_t)p * FM_PLANE_STRIDE
                          + ((size_t)(2 * y) * 512 + 2 * x) * 16 + q * 4;
    f4v r = avg4(ld4(sp), ld4(sp + 16), ld4(sp + 512 * 16), ld4(sp + 512 * 16 + 16));
    st4(dst + (size_t)p * WS_PLANE_STRIDE + ((size_t)y * 256 + x) * 16 + q * 4, r);
}

__global__ __launch_bounds__(256) void mip_tail_f(float* __restrict__ mips)
{
    const int tile = blockIdx.x, q = blockIdx.y, p = blockIdx.z;
    const int ty = tile >> 2, tx = tile & 3;
    const int tid = threadIdx.x;
    __shared__ f4v A[32 * 32];
    __shared__ f4v B[16 * 16];
    float* plane = mips + (size_t)p * WS_PLANE_STRIDE;
    const float* L1 = plane;
    float* L2 = plane + (size_t)65536 * 16;
    float* L3 = plane + (size_t)81920 * 16;
    float* L4 = plane + (size_t)86016 * 16;
    float* L5 = plane + (size_t)87040 * 16;
    float* L6 = plane + (size_t)87296 * 16;
    float* L7 = plane + (size_t)87360 * 16;

    #pragma unroll
    for (int k = 0; k < 4; ++k) {
        int li = tid + k * 256;
        int ly = li >> 5, lx = li & 31;
        int gy = ty * 32 + ly, gx = tx * 32 + lx;
        const float* sp = L1 + ((size_t)(2 * gy) * 256 + 2 * gx) * 16 + q * 4;
        f4v r = avg4(ld4(sp), ld4(sp + 16), ld4(sp + 256 * 16), ld4(sp + 256 * 16 + 16));
        A[li] = r;
        st4(L2 + ((size_t)gy * 128 + gx) * 16 + q * 4, r);
    }
    __syncthreads();
    {
        int ly = tid >> 4, lx = tid & 15;
        f4v r = avg4(A[(2 * ly) * 32 + 2 * lx],     A[(2 * ly) * 32 + 2 * lx + 1],
                     A[(2 * ly + 1) * 32 + 2 * lx], A[(2 * ly + 1) * 32 + 2 * lx + 1]);
        B[tid] = r;
        st4(L3 + ((size_t)(ty * 16 + ly) * 64 + tx * 16 + lx) * 16 + q * 4, r);
    }
    __syncthreads();
    if (tid < 64) {
        int ly = tid >> 3, lx = tid & 7;
        f4v r = avg4(B[(2 * ly) * 16 + 2 * lx],     B[(2 * ly) * 16 + 2 * lx + 1],
                     B[(2 * ly + 1) * 16 + 2 * lx], B[(2 * ly + 1) * 16 + 2 * lx + 1]);
        A[tid] = r;
        st4(L4 + ((size_t)(ty * 8 + ly) * 32 + tx * 8 + lx) * 16 + q * 4, r);
    }
    __syncthreads();
    if (tid < 16) {
        int ly = tid >> 2, lx = tid & 3;
        f4v r = avg4(A[(2 * ly) * 8 + 2 * lx],     A[(2 * ly) * 8 + 2 * lx + 1],
                     A[(2 * ly + 1) * 8 + 2 * lx], A[(2 * ly + 1) * 8 + 2 * lx + 1]);
        B[tid] = r;
        st4(L5 + ((size_t)(ty * 4 + ly) * 16 + tx * 4 + lx) * 16 + q * 4, r);
    }
    __syncthreads();
    if (tid < 4) {
        int ly = tid >> 1, lx = tid & 1;
        f4v r = avg4(B[(2 * ly) * 4 + 2 * lx],     B[(2 * ly) * 4 + 2 * lx + 1],
                     B[(2 * ly + 1) * 4 + 2 * lx], B[(2 * ly + 1) * 4 + 2 * lx + 1]);
        A[tid] = r;
        st4(L6 + ((size_t)(ty * 2 + ly) * 8 + tx * 2 + lx) * 16 + q * 4, r);
    }
    __syncthreads();
    if (tid == 0) {
        f4v r = avg4(A[0], A[1], A[2], A[3]);
        st4(L7 + ((size_t)ty * 4 + tx) * 16 + q * 4, r);
    }
}

__device__ __forceinline__ f4v bilerp_f(
    const float* __restrict__ fm, const float* __restrict__ mips,
    int p, int l, float u, float v, int q)
{
    const int sz = 512 >> l;
    const float fsz = (float)sz;
    float px = u * fsz - 0.5f;
    float py = v * fsz - 0.5f;
    float xf = floorf(px), yf = floorf(py);
    float fx = px - xf, fy = py - yf;
    int xi = (int)xf, yi = (int)yf;
    int xa = min(max(xi, 0), sz - 1);
    int xb = min(xi + 1, sz - 1);
    int ya = min(max(yi, 0), sz - 1);
    int yb = min(yi + 1, sz - 1);
    const float* base;
    if (l == 0) {
        base = fm + (size_t)p * FM_PLANE_STRIDE;
    } else {
        unsigned off = (262144u - ((unsigned)(sz * sz) << 2)) / 3u;
        base = mips + (size_t)p * WS_PLANE_STRIDE + (size_t)off * 16;
    }
    const float* r0 = base + (size_t)(ya * sz) * 16 + q * 4;
    const float* r1 = base + (size_t)(yb * sz) * 16 + q * 4;
    f4v f00 = ld4(r0 + xa * 16);
    f4v f01 = ld4(r0 + xb * 16);
    f4v f10 = ld4(r1 + xa * 16);
    f4v f11 = ld4(r1 + xb * 16);
    float gx = 1.f - fx, gy = 1.f - fy;
    return (f00 * gx + f01 * fx) * gy + (f10 * gx + f11 * fx) * fy;
}

__global__ __launch_bounds__(256) void trimip_sample_f(
    const float* __restrict__ xyz, const float* __restrict__ level,
    const float* __restrict__ fm, const float* __restrict__ mips,
    float* __restrict__ out, int N)
{
    int t = blockIdx.x * blockDim.x + threadIdx.x;
    if (t >= N * 12) return;
    const int q = t & 3;
    const int r = t >> 2;
    const int n = r / 3;
    const int p = r - n * 3;
    const float c0 = xyz[n * 3 + 0];
    const float c1 = xyz[n * 3 + 1];
    const float c2 = xyz[n * 3 + 2];
    const float u = (p == 0) ? c1 : c0;
    const float v = (p == 2) ? c1 : c2;
    float lv = level[n];
    lv = fminf(fmaxf(lv, 0.f), 7.f);
    float lf = floorf(lv);
    float f = lv - lf;
    int l0 = (int)lf;
    int l1 = min(l0 + 1, 7);
    f4v s0 = bilerp_f(fm, mips, p, l0, u, v, q);
    f4v s1 = bilerp_f(fm, mips, p, l1, u, v, q);
    f4v o = s0 * (1.f - f) + s1 * f;
    st4nt(out + (size_t)t * 4, o);
}

extern "C" void kernel_launch(void* const* d_in, const int* in_sizes, int n_in,
                              void* d_out, int out_size, void* d_ws, size_t ws_size,
                              hipStream_t stream) {
    const float* xyz   = (const float*)d_in[0];
    const float* level = (const float*)d_in[1];
    const float* fm    = (const float*)d_in[2];
    float* out = (float*)d_out;
    const int N = in_sizes[1];

    if (ws_size >= WS_H_BYTES) {
        __half* wsh = (__half*)d_ws;
        mip_build_all<<<dim3(64, 3), 1024, 0, stream>>>(fm, wsh);
        trimip_sample_h<<<dim3((N + 511) / 512, 3), 1024, 0, stream>>>(
            xyz, level, wsh, out, N);
    } else {
        float* mips = (float*)d_ws;
        mip_build_f<<<dim3(1024, 3), dim3(256), 0, stream>>>(fm, mips);
        mip_tail_f<<<dim3(16, 4, 3), dim3(256), 0, stream>>>(mips);
        const int total = N * 12;
        trimip_sample_f<<<(total + 255) / 256, 256, 0, stream>>>(xyz, level, fm, mips, out, N);
    }
}